// Round 10
// baseline (253.919 us; speedup 1.0000x reference)
//
#include <hip/hip_runtime.h>

#define EPS 1e-5f

typedef __attribute__((ext_vector_type(8))) short bf16x8;   // MFMA A/B frag (8 bf16)
typedef __attribute__((ext_vector_type(4))) float f32x4;    // MFMA C/D frag
typedef __attribute__((ext_vector_type(2))) unsigned int u32x2;
typedef __attribute__((ext_vector_type(4))) unsigned int u32x4;

__device__ __forceinline__ unsigned short f2bf(float f) {
    union { float f; unsigned int u; } c; c.f = f;
    unsigned int u = c.u;
    u += 0x7fffu + ((u >> 16) & 1u);
    return (unsigned short)(u >> 16);
}
// pack 2 f32 -> 2 bf16 (lo=a, hi=b), RNE
__device__ __forceinline__ unsigned int pkbf(float a, float b) {
    unsigned int d;
    asm("v_cvt_pk_bf16_f32 %0, %1, %2" : "=v"(d) : "v"(a), "v"(b));
    return d;
}

// ws layout (bytes) — weights stored 16x16x32-FRAGMENT-MAJOR:
//   elem(row,col), NKS=K/32:
//     dst = (((row>>4)*NKS + (col>>5))*64 + ((col>>3)&3)*16 + (row&15))*8 + (col&7)
//   [0,1536)        W1f   384 f32  (BN1-folded W1)
//   [1536,2048)     b1p   128 f32
//   [2048,4096)     b3p   512 f32  (BN3-folded bias)
//   [4096,69632)    W2f   256x128 bf16 frag  (NKS=4)
//   [69632,593920)  W3f   512x512 bf16 frag  (NKS=16; ks 0..7 = gf cols, 8..15 = pf cols)
//   [593920,987136) W4f   384x512 bf16 frag  (NKS=16)
//   [987136, +128M) pf    (split path) 4096 pairs x 32768 B frag-major bf16
//   [.., +16M)      u     (split path) 8192 groups x 512 f32

__global__ void prep_kernel(const float* __restrict__ W1, const float* __restrict__ b1,
                            const float* __restrict__ g1, const float* __restrict__ be1,
                            const float* __restrict__ m1, const float* __restrict__ v1,
                            const float* __restrict__ W2,
                            const float* __restrict__ W3, const float* __restrict__ b3,
                            const float* __restrict__ g3, const float* __restrict__ be3,
                            const float* __restrict__ m3, const float* __restrict__ v3,
                            const float* __restrict__ W4,
                            char* __restrict__ ws)
{
    float* W1f = (float*)ws;
    float* b1p = (float*)(ws + 1536);
    float* b3p = (float*)(ws + 2048);
    unsigned short* W2b = (unsigned short*)(ws + 4096);
    unsigned short* W3b = (unsigned short*)(ws + 69632);
    unsigned short* W4b = (unsigned short*)(ws + 593920);

    const int stride = gridDim.x * blockDim.x;
    for (int idx = blockIdx.x * blockDim.x + threadIdx.x; idx < 262144; idx += stride) {
        {
            int row = idx >> 9, col = idx & 511;
            float inv = g3[row] / sqrtf(v3[row] + EPS);
            int dst = (((row >> 4) * 16 + (col >> 5)) * 64 + ((col >> 3) & 3) * 16 + (row & 15)) * 8 + (col & 7);
            W3b[dst] = f2bf(W3[idx] * inv);
        }
        if (idx < 196608) {
            int row = idx >> 9, col = idx & 511;
            int dst = (((row >> 4) * 16 + (col >> 5)) * 64 + ((col >> 3) & 3) * 16 + (row & 15)) * 8 + (col & 7);
            W4b[dst] = f2bf(W4[idx]);
        }
        if (idx < 32768) {
            int row = idx >> 7, col = idx & 127;
            int dst = (((row >> 4) * 4 + (col >> 5)) * 64 + ((col >> 3) & 3) * 16 + (row & 15)) * 8 + (col & 7);
            W2b[dst] = f2bf(W2[idx]);
        }
        if (idx < 384) {
            int c = idx / 3;
            float inv = g1[c] / sqrtf(v1[c] + EPS);
            W1f[idx] = W1[idx] * inv;
        }
        if (idx < 128) {
            float inv = g1[idx] / sqrtf(v1[idx] + EPS);
            b1p[idx] = b1[idx] * inv + be1[idx] - m1[idx] * inv;
        }
        if (idx < 512) {
            float inv = g3[idx] / sqrtf(v3[idx] + EPS);
            b3p[idx] = b3[idx] * inv + be3[idx] - m3[idx] * inv;
        }
    }
}

// ================= split path: K1 = L1 + L2 + u =================
// LDS: HT [0,16K) 4 tiles x 4K; GF [16K,17K+)
#define K1_OFF_HT 0
#define K1_OFF_GF 16384
#define K1_SMEM   17536

__global__ __launch_bounds__(512, 4)
void pf_kernel(const float* __restrict__ pg,
               const float* __restrict__ b2,
               const char* __restrict__ ws,
               char* __restrict__ pfb,
               float* __restrict__ ub)
{
    const float* W1f = (const float*)ws;
    const float* b1p = (const float*)(ws + 1536);
    const unsigned short* W2b = (const unsigned short*)(ws + 4096);
    const unsigned short* W3b = (const unsigned short*)(ws + 69632);

    __shared__ char sm[K1_SMEM];

    const int tid  = (int)threadIdx.x;
    const int wave = __builtin_amdgcn_readfirstlane(tid >> 6);
    const int lane = tid & 63;
    const int l15  = lane & 15;
    const int lq   = lane >> 4;
    const int n0   = (int)blockIdx.x * 2;

    // ---- Layer 1 (fp32): hT -> HT (B-frag layout) ----
    {
        const int g = lane >> 5, k = lane & 31;
        const float* xp = pg + ((size_t)(n0 + g) * 32 + k) * 3;
        const float x0 = xp[0], x1 = xp[1], x2 = xp[2];
        const int c0 = wave * 16;
        float v[16];
        #pragma unroll
        for (int j = 0; j < 16; ++j) {
            const int c = c0 + j;
            float t = fmaf(W1f[c*3+0], x0, fmaf(W1f[c*3+1], x1, fmaf(W1f[c*3+2], x2, b1p[c])));
            v[j] = fmaxf(t, 0.f);
        }
        u32x4 w0, w1;
        #pragma unroll
        for (int k2 = 0; k2 < 4; ++k2) {
            w0[k2] = pkbf(v[2*k2],   v[2*k2+1]);
            w1[k2] = pkbf(v[8+2*k2], v[8+2*k2+1]);
        }
        char* base = sm + K1_OFF_HT + (lane>>4)*4096 + (wave>>1)*1024 + (wave&1)*512 + l15*16;
        *(u32x4*)(base)       = w0;
        *(u32x4*)(base + 256) = w1;
    }
    __syncthreads();

    // ---- Layer 2 (MFMA, K=128): pf -> GLOBAL (frag-major), gf -> LDS ----
    {
        f32x4 bias2[2];
        #pragma unroll
        for (int mt = 0; mt < 2; ++mt)
            bias2[mt] = *(const f32x4*)(b2 + (wave*2 + mt)*16 + lq*4);

        f32x4 acc[2][4];
        #pragma unroll
        for (int mt = 0; mt < 2; ++mt)
            #pragma unroll
            for (int nt = 0; nt < 4; ++nt) acc[mt][nt] = bias2[mt];

        __builtin_amdgcn_s_setprio(1);
        #pragma unroll
        for (int ks = 0; ks < 4; ++ks) {
            bf16x8 A[2], Bv[4];
            #pragma unroll
            for (int mt = 0; mt < 2; ++mt)
                A[mt] = *(const bf16x8*)(W2b + ((wave*2 + mt)*4 + ks)*512 + lane*8);
            #pragma unroll
            for (int nt = 0; nt < 4; ++nt)
                Bv[nt] = *(const bf16x8*)(sm + K1_OFF_HT + nt*4096 + ks*1024 + lane*16);
            #pragma unroll
            for (int mt = 0; mt < 2; ++mt)
                #pragma unroll
                for (int nt = 0; nt < 4; ++nt)
                    acc[mt][nt] = __builtin_amdgcn_mfma_f32_16x16x32_bf16(A[mt], Bv[nt], acc[mt][nt], 0, 0, 0);
        }
        __builtin_amdgcn_s_setprio(0);

        char* pfd = pfb + (size_t)blockIdx.x * 32768;
        #pragma unroll
        for (int mt = 0; mt < 2; ++mt) {
            const int row0 = (wave*2 + mt)*16 + lq*4;
            const int roff = (row0>>5)*1024 + ((row0&31)>>3)*256 + l15*16 + (row0&7)*2;
            float gmax[2][4];
            #pragma unroll
            for (int nt = 0; nt < 4; ++nt) {
                const int g = nt >> 1;
                u32x2 w;
                w[0] = pkbf(acc[mt][nt][0], acc[mt][nt][1]);
                w[1] = pkbf(acc[mt][nt][2], acc[mt][nt][3]);
                *(u32x2*)(pfd + nt*8192 + roff) = w;
                #pragma unroll
                for (int r = 0; r < 4; ++r) {
                    if ((nt & 1) == 0) gmax[g][r] = acc[mt][nt][r];
                    else               gmax[g][r] = fmaxf(gmax[g][r], acc[mt][nt][r]);
                }
            }
            #pragma unroll
            for (int m = 1; m < 16; m <<= 1)
                #pragma unroll
                for (int g = 0; g < 2; ++g)
                    #pragma unroll
                    for (int r = 0; r < 4; ++r)
                        gmax[g][r] = fmaxf(gmax[g][r], __shfl_xor(gmax[g][r], m));
            if (l15 < 2) {
                u32x2 w;
                w[0] = pkbf(gmax[l15][0], gmax[l15][1]);
                w[1] = pkbf(gmax[l15][2], gmax[l15][3]);
                *(u32x2*)(sm + K1_OFF_GF + (row0>>5)*128 + ((row0&31)>>3)*32 + l15*16 + (row0&7)*2) = w;
            }
        }
    }
    __syncthreads();

    // ---- u = W3[:,0:256] @ gf (N=16 MFMA) -> GLOBAL ----
    {
        f32x4 au[4];
        #pragma unroll
        for (int mt = 0; mt < 4; ++mt) au[mt] = (f32x4){0.f,0.f,0.f,0.f};

        const char* gfb = sm + K1_OFF_GF + lq*32 + (l15 & 1)*16;
        __builtin_amdgcn_s_setprio(1);
        #pragma unroll 2
        for (int ks = 0; ks < 8; ++ks) {
            bf16x8 Bg = *(const bf16x8*)(gfb + ks*128);
            #pragma unroll
            for (int mt = 0; mt < 4; ++mt) {
                bf16x8 A = *(const bf16x8*)(W3b + ((wave*4 + mt)*16 + ks)*512 + lane*8);
                au[mt] = __builtin_amdgcn_mfma_f32_16x16x32_bf16(A, Bg, au[mt], 0, 0, 0);
            }
        }
        __builtin_amdgcn_s_setprio(0);
        if (l15 < 2) {
            #pragma unroll
            for (int mt = 0; mt < 4; ++mt)
                *(f32x4*)(ub + (size_t)(n0 + l15)*512 + (wave*4 + mt)*16 + lq*4) = au[mt];
        }
    }
}

// ================= split path: K2 = L3 + L4 =================
// LDS: PF [0,32K) staged from global; H2 [0,64K) aliases PF (written post-barrier);
//      U [64K,68K) 2 groups x 512 f32
#define K2_OFF_PF 0
#define K2_OFF_H2 0
#define K2_OFF_U  65536
#define K2_SMEM   69632

__global__ __launch_bounds__(512, 4)
void l34_kernel(const float* __restrict__ b4,
                const char* __restrict__ ws,
                const char* __restrict__ pfb,
                const float* __restrict__ ub,
                float* __restrict__ out)
{
    const float* b3p = (const float*)(ws + 2048);
    const unsigned short* W3b = (const unsigned short*)(ws + 69632);
    const unsigned short* W4b = (const unsigned short*)(ws + 593920);

    __shared__ char sm[K2_SMEM];

    const int tid  = (int)threadIdx.x;
    const int wave = __builtin_amdgcn_readfirstlane(tid >> 6);
    const int lane = tid & 63;
    const int l15  = lane & 15;
    const int lq   = lane >> 4;
    const int n0   = (int)blockIdx.x * 2;

    // ---- stage PF (32 KB) and u (4 KB) into LDS ----
    {
        const char* src = pfb + (size_t)blockIdx.x * 32768;
        #pragma unroll
        for (int i = 0; i < 4; ++i) {
            u32x4 v = *(const u32x4*)(src + (tid + i*512)*16);
            *(u32x4*)(sm + K2_OFF_PF + (tid + i*512)*16) = v;
        }
        float* uld = (float*)(sm + K2_OFF_U);
        uld[tid]       = ub[(size_t)n0*512 + tid];
        uld[512 + tid] = ub[(size_t)n0*512 + 512 + tid];
    }
    __syncthreads();

    // ---- Layer 3 (MFMA, K=256 over pf): b3p folded into acc init ----
    {
        f32x4 bias3[4];
        #pragma unroll
        for (int mt = 0; mt < 4; ++mt)
            bias3[mt] = *(const f32x4*)(b3p + (wave*4 + mt)*16 + lq*4);

        f32x4 acc[4][4];
        #pragma unroll
        for (int mt = 0; mt < 4; ++mt)
            #pragma unroll
            for (int nt = 0; nt < 4; ++nt) acc[mt][nt] = bias3[mt];

        __builtin_amdgcn_s_setprio(1);
        #pragma unroll 2
        for (int ks = 0; ks < 8; ++ks) {
            bf16x8 A[4], Bv[4];
            #pragma unroll
            for (int mt = 0; mt < 4; ++mt)
                A[mt] = *(const bf16x8*)(W3b + ((wave*4 + mt)*16 + 8 + ks)*512 + lane*8);
            #pragma unroll
            for (int nt = 0; nt < 4; ++nt)
                Bv[nt] = *(const bf16x8*)(sm + K2_OFF_PF + nt*8192 + ks*1024 + lane*16);
            #pragma unroll
            for (int mt = 0; mt < 4; ++mt)
                #pragma unroll
                for (int nt = 0; nt < 4; ++nt)
                    acc[mt][nt] = __builtin_amdgcn_mfma_f32_16x16x32_bf16(A[mt], Bv[nt], acc[mt][nt], 0, 0, 0);
        }
        __builtin_amdgcn_s_setprio(0);

        __syncthreads();   // PF reads done; H2 may overwrite alias region

        const float* u = (const float*)(sm + K2_OFF_U);
        #pragma unroll
        for (int mt = 0; mt < 4; ++mt) {
            const int row0 = (wave*4 + mt)*16 + lq*4;
            const int roff = (row0>>5)*1024 + ((row0&31)>>3)*256 + l15*16 + (row0&7)*2;
            f32x4 u0 = *(const f32x4*)(u + row0);
            f32x4 u1 = *(const f32x4*)(u + 512 + row0);
            #pragma unroll
            for (int nt = 0; nt < 4; ++nt) {
                const f32x4 ug = (nt >> 1) ? u1 : u0;
                float v[4];
                #pragma unroll
                for (int r = 0; r < 4; ++r)
                    v[r] = fmaxf(acc[mt][nt][r] + ug[r], 0.f);
                u32x2 w;
                w[0] = pkbf(v[0], v[1]);
                w[1] = pkbf(v[2], v[3]);
                *(u32x2*)(sm + K2_OFF_H2 + nt*16384 + roff) = w;
            }
        }
    }
    __syncthreads();

    // ---- Layer 4 (MFMA, K=512): out = max_k (W4 h2) + b4 ----
    {
        f32x4 acc[3][4];
        #pragma unroll
        for (int mt = 0; mt < 3; ++mt)
            #pragma unroll
            for (int nt = 0; nt < 4; ++nt) acc[mt][nt] = (f32x4){0.f,0.f,0.f,0.f};

        __builtin_amdgcn_s_setprio(1);
        #pragma unroll 2
        for (int ks = 0; ks < 16; ++ks) {
            bf16x8 A[3], Bv[4];
            #pragma unroll
            for (int mt = 0; mt < 3; ++mt)
                A[mt] = *(const bf16x8*)(W4b + ((wave*3 + mt)*16 + ks)*512 + lane*8);
            #pragma unroll
            for (int nt = 0; nt < 4; ++nt)
                Bv[nt] = *(const bf16x8*)(sm + K2_OFF_H2 + nt*16384 + ks*1024 + lane*16);
            #pragma unroll
            for (int mt = 0; mt < 3; ++mt)
                #pragma unroll
                for (int nt = 0; nt < 4; ++nt)
                    acc[mt][nt] = __builtin_amdgcn_mfma_f32_16x16x32_bf16(A[mt], Bv[nt], acc[mt][nt], 0, 0, 0);
        }
        __builtin_amdgcn_s_setprio(0);

        #pragma unroll
        for (int mt = 0; mt < 3; ++mt) {
            const int row0 = (wave*3 + mt)*16 + lq*4;
            float gmax[2][4];
            #pragma unroll
            for (int g = 0; g < 2; ++g)
                #pragma unroll
                for (int r = 0; r < 4; ++r)
                    gmax[g][r] = fmaxf(acc[mt][2*g][r], acc[mt][2*g+1][r]);
            #pragma unroll
            for (int m = 1; m < 16; m <<= 1)
                #pragma unroll
                for (int g = 0; g < 2; ++g)
                    #pragma unroll
                    for (int r = 0; r < 4; ++r)
                        gmax[g][r] = fmaxf(gmax[g][r], __shfl_xor(gmax[g][r], m));
            if (l15 < 2) {
                const int g = l15;
                f32x4 b = *(const f32x4*)(b4 + row0);
                f32x4 o;
                #pragma unroll
                for (int r = 0; r < 4; ++r) o[r] = gmax[g][r] + b[r];
                *(f32x4*)(out + (size_t)(n0 + g) * 384 + row0) = o;
            }
        }
    }
}

// ================= fallback monolith (R8, proven) =================
#define OFF_HT 0
#define OFF_PF 16384
#define OFF_H2 0
#define OFF_U  65536
#define OFF_GF 69632
#define SMEM_BYTES 70784

__global__ __launch_bounds__(512, 4)
void patch_kernel(const float* __restrict__ pg,
                  const float* __restrict__ b2,
                  const float* __restrict__ b4,
                  const char* __restrict__ ws,
                  float* __restrict__ out)
{
    const float* W1f = (const float*)ws;
    const float* b1p = (const float*)(ws + 1536);
    const float* b3p = (const float*)(ws + 2048);
    const unsigned short* W2b = (const unsigned short*)(ws + 4096);
    const unsigned short* W3b = (const unsigned short*)(ws + 69632);
    const unsigned short* W4b = (const unsigned short*)(ws + 593920);

    __shared__ char sm[SMEM_BYTES];

    const int tid  = (int)threadIdx.x;
    const int wave = __builtin_amdgcn_readfirstlane(tid >> 6);
    const int lane = tid & 63;
    const int l15  = lane & 15;
    const int lq   = lane >> 4;
    const int n0   = (int)blockIdx.x * 2;

    {
        const int g = lane >> 5, k = lane & 31;
        const float* xp = pg + ((size_t)(n0 + g) * 32 + k) * 3;
        const float x0 = xp[0], x1 = xp[1], x2 = xp[2];
        const int c0 = wave * 16;
        float v[16];
        #pragma unroll
        for (int j = 0; j < 16; ++j) {
            const int c = c0 + j;
            float t = fmaf(W1f[c*3+0], x0, fmaf(W1f[c*3+1], x1, fmaf(W1f[c*3+2], x2, b1p[c])));
            v[j] = fmaxf(t, 0.f);
        }
        u32x4 w0, w1;
        #pragma unroll
        for (int k2 = 0; k2 < 4; ++k2) {
            w0[k2] = pkbf(v[2*k2],   v[2*k2+1]);
            w1[k2] = pkbf(v[8+2*k2], v[8+2*k2+1]);
        }
        char* base = sm + OFF_HT + (lane>>4)*4096 + (wave>>1)*1024 + (wave&1)*512 + l15*16;
        *(u32x4*)(base)       = w0;
        *(u32x4*)(base + 256) = w1;
    }
    __syncthreads();

    {
        f32x4 bias2[2];
        #pragma unroll
        for (int mt = 0; mt < 2; ++mt)
            bias2[mt] = *(const f32x4*)(b2 + (wave*2 + mt)*16 + lq*4);

        f32x4 acc[2][4];
        #pragma unroll
        for (int mt = 0; mt < 2; ++mt)
            #pragma unroll
            for (int nt = 0; nt < 4; ++nt) acc[mt][nt] = bias2[mt];

        __builtin_amdgcn_s_setprio(1);
        #pragma unroll
        for (int ks = 0; ks < 4; ++ks) {
            bf16x8 A[2], Bv[4];
            #pragma unroll
            for (int mt = 0; mt < 2; ++mt)
                A[mt] = *(const bf16x8*)(W2b + ((wave*2 + mt)*4 + ks)*512 + lane*8);
            #pragma unroll
            for (int nt = 0; nt < 4; ++nt)
                Bv[nt] = *(const bf16x8*)(sm + OFF_HT + nt*4096 + ks*1024 + lane*16);
            #pragma unroll
            for (int mt = 0; mt < 2; ++mt)
                #pragma unroll
                for (int nt = 0; nt < 4; ++nt)
                    acc[mt][nt] = __builtin_amdgcn_mfma_f32_16x16x32_bf16(A[mt], Bv[nt], acc[mt][nt], 0, 0, 0);
        }
        __builtin_amdgcn_s_setprio(0);

        #pragma unroll
        for (int mt = 0; mt < 2; ++mt) {
            const int row0 = (wave*2 + mt)*16 + lq*4;
            const int roff = (row0>>5)*1024 + ((row0&31)>>3)*256 + l15*16 + (row0&7)*2;
            float gmax[2][4];
            #pragma unroll
            for (int nt = 0; nt < 4; ++nt) {
                const int g = nt >> 1;
                u32x2 w;
                w[0] = pkbf(acc[mt][nt][0], acc[mt][nt][1]);
                w[1] = pkbf(acc[mt][nt][2], acc[mt][nt][3]);
                *(u32x2*)(sm + OFF_PF + nt*8192 + roff) = w;
                #pragma unroll
                for (int r = 0; r < 4; ++r) {
                    if ((nt & 1) == 0) gmax[g][r] = acc[mt][nt][r];
                    else               gmax[g][r] = fmaxf(gmax[g][r], acc[mt][nt][r]);
                }
            }
            #pragma unroll
            for (int m = 1; m < 16; m <<= 1)
                #pragma unroll
                for (int g = 0; g < 2; ++g)
                    #pragma unroll
                    for (int r = 0; r < 4; ++r)
                        gmax[g][r] = fmaxf(gmax[g][r], __shfl_xor(gmax[g][r], m));
            if (l15 < 2) {
                u32x2 w;
                w[0] = pkbf(gmax[l15][0], gmax[l15][1]);
                w[1] = pkbf(gmax[l15][2], gmax[l15][3]);
                *(u32x2*)(sm + OFF_GF + (row0>>5)*128 + ((row0&31)>>3)*32 + l15*16 + (row0&7)*2) = w;
            }
        }
    }
    __syncthreads();

    {
        f32x4 au[4];
        #pragma unroll
        for (int mt = 0; mt < 4; ++mt) au[mt] = (f32x4){0.f,0.f,0.f,0.f};

        const char* gfb = sm + OFF_GF + lq*32 + (l15 & 1)*16;
        __builtin_amdgcn_s_setprio(1);
        #pragma unroll 2
        for (int ks = 0; ks < 8; ++ks) {
            bf16x8 Bg = *(const bf16x8*)(gfb + ks*128);
            #pragma unroll
            for (int mt = 0; mt < 4; ++mt) {
                bf16x8 A = *(const bf16x8*)(W3b + ((wave*4 + mt)*16 + ks)*512 + lane*8);
                au[mt] = __builtin_amdgcn_mfma_f32_16x16x32_bf16(A, Bg, au[mt], 0, 0, 0);
            }
        }
        __builtin_amdgcn_s_setprio(0);
        if (l15 < 2) {
            float* u = (float*)(sm + OFF_U);
            #pragma unroll
            for (int mt = 0; mt < 4; ++mt)
                #pragma unroll
                for (int r = 0; r < 4; ++r)
                    u[l15*512 + (wave*4 + mt)*16 + lq*4 + r] = au[mt][r];
        }
    }

    {
        f32x4 bias3[4];
        #pragma unroll
        for (int mt = 0; mt < 4; ++mt)
            bias3[mt] = *(const f32x4*)(b3p + (wave*4 + mt)*16 + lq*4);

        f32x4 acc[4][4];
        #pragma unroll
        for (int mt = 0; mt < 4; ++mt)
            #pragma unroll
            for (int nt = 0; nt < 4; ++nt) acc[mt][nt] = bias3[mt];

        __builtin_amdgcn_s_setprio(1);
        #pragma unroll 2
        for (int ks = 0; ks < 8; ++ks) {
            bf16x8 A[4], Bv[4];
            #pragma unroll
            for (int mt = 0; mt < 4; ++mt)
                A[mt] = *(const bf16x8*)(W3b + ((wave*4 + mt)*16 + 8 + ks)*512 + lane*8);
            #pragma unroll
            for (int nt = 0; nt < 4; ++nt)
                Bv[nt] = *(const bf16x8*)(sm + OFF_PF + nt*8192 + ks*1024 + lane*16);
            #pragma unroll
            for (int mt = 0; mt < 4; ++mt)
                #pragma unroll
                for (int nt = 0; nt < 4; ++nt)
                    acc[mt][nt] = __builtin_amdgcn_mfma_f32_16x16x32_bf16(A[mt], Bv[nt], acc[mt][nt], 0, 0, 0);
        }
        __builtin_amdgcn_s_setprio(0);

        __syncthreads();

        const float* u = (const float*)(sm + OFF_U);
        #pragma unroll
        for (int mt = 0; mt < 4; ++mt) {
            const int row0 = (wave*4 + mt)*16 + lq*4;
            const int roff = (row0>>5)*1024 + ((row0&31)>>3)*256 + l15*16 + (row0&7)*2;
            f32x4 u0 = *(const f32x4*)(u + row0);
            f32x4 u1 = *(const f32x4*)(u + 512 + row0);
            #pragma unroll
            for (int nt = 0; nt < 4; ++nt) {
                const f32x4 ug = (nt >> 1) ? u1 : u0;
                float v[4];
                #pragma unroll
                for (int r = 0; r < 4; ++r)
                    v[r] = fmaxf(acc[mt][nt][r] + ug[r], 0.f);
                u32x2 w;
                w[0] = pkbf(v[0], v[1]);
                w[1] = pkbf(v[2], v[3]);
                *(u32x2*)(sm + OFF_H2 + nt*16384 + roff) = w;
            }
        }
    }
    __syncthreads();

    {
        f32x4 acc[3][4];
        #pragma unroll
        for (int mt = 0; mt < 3; ++mt)
            #pragma unroll
            for (int nt = 0; nt < 4; ++nt) acc[mt][nt] = (f32x4){0.f,0.f,0.f,0.f};

        __builtin_amdgcn_s_setprio(1);
        #pragma unroll 2
        for (int ks = 0; ks < 16; ++ks) {
            bf16x8 A[3], Bv[4];
            #pragma unroll
            for (int mt = 0; mt < 3; ++mt)
                A[mt] = *(const bf16x8*)(W4b + ((wave*3 + mt)*16 + ks)*512 + lane*8);
            #pragma unroll
            for (int nt = 0; nt < 4; ++nt)
                Bv[nt] = *(const bf16x8*)(sm + OFF_H2 + nt*16384 + ks*1024 + lane*16);
            #pragma unroll
            for (int mt = 0; mt < 3; ++mt)
                #pragma unroll
                for (int nt = 0; nt < 4; ++nt)
                    acc[mt][nt] = __builtin_amdgcn_mfma_f32_16x16x32_bf16(A[mt], Bv[nt], acc[mt][nt], 0, 0, 0);
        }
        __builtin_amdgcn_s_setprio(0);

        #pragma unroll
        for (int mt = 0; mt < 3; ++mt) {
            const int row0 = (wave*3 + mt)*16 + lq*4;
            float gmax[2][4];
            #pragma unroll
            for (int g = 0; g < 2; ++g)
                #pragma unroll
                for (int r = 0; r < 4; ++r)
                    gmax[g][r] = fmaxf(acc[mt][2*g][r], acc[mt][2*g+1][r]);
            #pragma unroll
            for (int m = 1; m < 16; m <<= 1)
                #pragma unroll
                for (int g = 0; g < 2; ++g)
                    #pragma unroll
                    for (int r = 0; r < 4; ++r)
                        gmax[g][r] = fmaxf(gmax[g][r], __shfl_xor(gmax[g][r], m));
            if (l15 < 2) {
                const int g = l15;
                f32x4 b = *(const f32x4*)(b4 + row0);
                f32x4 o;
                #pragma unroll
                for (int r = 0; r < 4; ++r) o[r] = gmax[g][r] + b[r];
                *(f32x4*)(out + (size_t)(n0 + g) * 384 + row0) = o;
            }
        }
    }
}

extern "C" void kernel_launch(void* const* d_in, const int* in_sizes, int n_in,
                              void* d_out, int out_size, void* d_ws, size_t ws_size,
                              hipStream_t stream) {
    const float* pg  = (const float*)d_in[0];
    const float* W1  = (const float*)d_in[1];
    const float* b1  = (const float*)d_in[2];
    const float* g1  = (const float*)d_in[3];
    const float* be1 = (const float*)d_in[4];
    const float* m1  = (const float*)d_in[5];
    const float* v1  = (const float*)d_in[6];
    const float* W2  = (const float*)d_in[7];
    const float* b2  = (const float*)d_in[8];
    const float* W3  = (const float*)d_in[9];
    const float* b3  = (const float*)d_in[10];
    const float* g3  = (const float*)d_in[11];
    const float* be3 = (const float*)d_in[12];
    const float* m3  = (const float*)d_in[13];
    const float* v3  = (const float*)d_in[14];
    const float* W4  = (const float*)d_in[15];
    const float* b4  = (const float*)d_in[16];
    float* out = (float*)d_out;
    char* ws = (char*)d_ws;

    const size_t PF_OFF = 987136;
    const size_t U_OFF  = PF_OFF + 134217728ull;   // pf: 4096 pairs * 32768 B
    const size_t NEED   = U_OFF + 16777216ull;     // u: 8192 * 512 * 4 B

    prep_kernel<<<dim3(256), dim3(256), 0, stream>>>(W1, b1, g1, be1, m1, v1, W2,
                                                     W3, b3, g3, be3, m3, v3, W4, ws);
    if (ws_size >= NEED) {
        pf_kernel<<<dim3(4096), dim3(512), 0, stream>>>(pg, b2, ws, ws + PF_OFF,
                                                        (float*)(ws + U_OFF));
        l34_kernel<<<dim3(4096), dim3(512), 0, stream>>>(b4, ws, ws + PF_OFF,
                                                         (const float*)(ws + U_OFF), out);
    } else {
        patch_kernel<<<dim3(4096), dim3(512), 0, stream>>>(pg, b2, b4, ws, out);
    }
    (void)in_sizes; (void)n_in; (void)out_size;
}

// Round 12
// 227.589 us; speedup vs baseline: 1.1157x; 1.1157x over previous
//
#include <hip/hip_runtime.h>

#define EPS 1e-5f

typedef __attribute__((ext_vector_type(8))) short bf16x8;   // MFMA A/B frag (8 bf16)
typedef __attribute__((ext_vector_type(4))) float f32x4;    // MFMA C/D frag
typedef __attribute__((ext_vector_type(2))) unsigned int u32x2;
typedef __attribute__((ext_vector_type(4))) unsigned int u32x4;

__device__ __forceinline__ unsigned short f2bf(float f) {
    union { float f; unsigned int u; } c; c.f = f;
    unsigned int u = c.u;
    u += 0x7fffu + ((u >> 16) & 1u);
    return (unsigned short)(u >> 16);
}
// pack 2 f32 -> 2 bf16 (lo=a, hi=b), RNE
__device__ __forceinline__ unsigned int pkbf(float a, float b) {
    unsigned int d;
    asm("v_cvt_pk_bf16_f32 %0, %1, %2" : "=v"(d) : "v"(a), "v"(b));
    return d;
}

// ws layout (bytes) — weights stored 16x16x32-FRAGMENT-MAJOR:
//   elem(row,col), NKS=K/32:
//     dst = (((row>>4)*NKS + (col>>5))*64 + ((col>>3)&3)*16 + (row&15))*8 + (col&7)
//   [0,1536)        W1f   384 f32  (BN1-folded W1)
//   [1536,2048)     b1p   128 f32
//   [2048,4096)     b3p   512 f32  (BN3-folded bias)
//   [4096,69632)    W2f   256x128 bf16 frag  (NKS=4)
//   [69632,593920)  W3f   512x512 bf16 frag  (NKS=16; ks 0..7 = gf cols, 8..15 = pf cols)
//   [593920,987136) W4f   384x512 bf16 frag  (NKS=16)

__global__ void prep_kernel(const float* __restrict__ W1, const float* __restrict__ b1,
                            const float* __restrict__ g1, const float* __restrict__ be1,
                            const float* __restrict__ m1, const float* __restrict__ v1,
                            const float* __restrict__ W2,
                            const float* __restrict__ W3, const float* __restrict__ b3,
                            const float* __restrict__ g3, const float* __restrict__ be3,
                            const float* __restrict__ m3, const float* __restrict__ v3,
                            const float* __restrict__ W4,
                            char* __restrict__ ws)
{
    float* W1f = (float*)ws;
    float* b1p = (float*)(ws + 1536);
    float* b3p = (float*)(ws + 2048);
    unsigned short* W2b = (unsigned short*)(ws + 4096);
    unsigned short* W3b = (unsigned short*)(ws + 69632);
    unsigned short* W4b = (unsigned short*)(ws + 593920);

    const int stride = gridDim.x * blockDim.x;
    for (int idx = blockIdx.x * blockDim.x + threadIdx.x; idx < 262144; idx += stride) {
        {
            int row = idx >> 9, col = idx & 511;
            float inv = g3[row] / sqrtf(v3[row] + EPS);
            int dst = (((row >> 4) * 16 + (col >> 5)) * 64 + ((col >> 3) & 3) * 16 + (row & 15)) * 8 + (col & 7);
            W3b[dst] = f2bf(W3[idx] * inv);
        }
        if (idx < 196608) {
            int row = idx >> 9, col = idx & 511;
            int dst = (((row >> 4) * 16 + (col >> 5)) * 64 + ((col >> 3) & 3) * 16 + (row & 15)) * 8 + (col & 7);
            W4b[dst] = f2bf(W4[idx]);
        }
        if (idx < 32768) {
            int row = idx >> 7, col = idx & 127;
            int dst = (((row >> 4) * 4 + (col >> 5)) * 64 + ((col >> 3) & 3) * 16 + (row & 15)) * 8 + (col & 7);
            W2b[dst] = f2bf(W2[idx]);
        }
        if (idx < 384) {
            int c = idx / 3;
            float inv = g1[c] / sqrtf(v1[c] + EPS);
            W1f[idx] = W1[idx] * inv;
        }
        if (idx < 128) {
            float inv = g1[idx] / sqrtf(v1[idx] + EPS);
            b1p[idx] = b1[idx] * inv + be1[idx] - m1[idx] * inv;
        }
        if (idx < 512) {
            float inv = g3[idx] / sqrtf(v3[idx] + EPS);
            b3p[idx] = b3[idx] * inv + be3[idx] - m3[idx] * inv;
        }
    }
}

// 4-group block (N=128 cols), 1024 threads = 16 waves (8 row-blocks x 2 col-halves).
// LDS, all tiles 16x16x32 B-FRAG-MAJOR (elem(col,ch) at
//   ntile*(CH*32) + (ch>>5)*1024 + ((ch&31)>>3)*256 + (col&15)*16 + (ch&7)*2):
//   HT [0,32K)      8 tiles x 4K   (128 ch)   dead after L2
//   PF [32K,96K)    8 tiles x 8K   (256 ch)   dead after L3 ks-loop
//   H2 [0,128K)     8 tiles x 16K  (512 ch)   ALIASES HT+PF (written post-L3-barrier)
//   GF [128K,+2K)   compact 4-col gf: (ch>>5)*256 + ((ch&31)>>3)*64 + col*16 + (ch&7)*2
//   U  [130K,+8K)   4 groups x 512 f32
#define OFF_HT 0
#define OFF_PF 32768
#define OFF_H2 0
#define OFF_GF 131072
#define OFF_U  133120
#define SMEM_BYTES 141312

__global__ __launch_bounds__(1024, 4)
void patch4_kernel(const float* __restrict__ pg,
                   const float* __restrict__ b2,
                   const float* __restrict__ b4,
                   const char* __restrict__ ws,
                   float* __restrict__ out)
{
    const float* W1f = (const float*)ws;
    const float* b1p = (const float*)(ws + 1536);
    const float* b3p = (const float*)(ws + 2048);
    const unsigned short* W2b = (const unsigned short*)(ws + 4096);
    const unsigned short* W3b = (const unsigned short*)(ws + 69632);
    const unsigned short* W4b = (const unsigned short*)(ws + 593920);

    __shared__ char sm[SMEM_BYTES];

    const int tid  = (int)threadIdx.x;
    const int wave = __builtin_amdgcn_readfirstlane(tid >> 6);   // 0..15
    const int lane = tid & 63;
    const int l15  = lane & 15;
    const int lq   = lane >> 4;
    const int wc   = wave & 1;          // col-half: nt = wc*4 + j
    const int wr   = wave >> 1;         // row-block 0..7
    const int n0   = (int)blockIdx.x * 4;

    // ---- Layer 1 (fp32): 128 cols x 128 ch -> HT (B-frag layout) ----
    {
        const int col = (wave & 1) * 64 + lane;       // 0..127
        const int W   = wave >> 1;                    // ch-block 0..7
        const int c0  = W * 16;
        const int g = col >> 5, k = col & 31;
        const float* xp = pg + ((size_t)(n0 + g) * 32 + k) * 3;
        const float x0 = xp[0], x1 = xp[1], x2 = xp[2];
        float v[16];
        #pragma unroll
        for (int j = 0; j < 16; ++j) {
            const int c = c0 + j;
            float t = fmaf(W1f[c*3+0], x0, fmaf(W1f[c*3+1], x1, fmaf(W1f[c*3+2], x2, b1p[c])));
            v[j] = fmaxf(t, 0.f);
        }
        u32x4 w0, w1;
        #pragma unroll
        for (int k2 = 0; k2 < 4; ++k2) {
            w0[k2] = pkbf(v[2*k2],   v[2*k2+1]);
            w1[k2] = pkbf(v[8+2*k2], v[8+2*k2+1]);
        }
        char* base = sm + OFF_HT + (col>>4)*4096 + (W>>1)*1024 + (W&1)*512 + (col&15)*16;
        *(u32x4*)(base)       = w0;
        *(u32x4*)(base + 256) = w1;
    }
    __syncthreads();

    // ---- Layer 2 (MFMA, K=128): pf + per-group max -> gf ----
    {
        f32x4 bias2[2];
        #pragma unroll
        for (int m = 0; m < 2; ++m)
            bias2[m] = *(const f32x4*)(b2 + (wr*2 + m)*16 + lq*4);

        f32x4 acc[2][4];
        #pragma unroll
        for (int m = 0; m < 2; ++m)
            #pragma unroll
            for (int j = 0; j < 4; ++j) acc[m][j] = bias2[m];

        __builtin_amdgcn_s_setprio(1);
        #pragma unroll
        for (int ks = 0; ks < 4; ++ks) {
            bf16x8 A[2], Bv[4];
            #pragma unroll
            for (int m = 0; m < 2; ++m)
                A[m] = *(const bf16x8*)(W2b + ((wr*2 + m)*4 + ks)*512 + lane*8);
            #pragma unroll
            for (int j = 0; j < 4; ++j)
                Bv[j] = *(const bf16x8*)(sm + OFF_HT + (wc*4 + j)*4096 + ks*1024 + lane*16);
            #pragma unroll
            for (int m = 0; m < 2; ++m)
                #pragma unroll
                for (int j = 0; j < 4; ++j)
                    acc[m][j] = __builtin_amdgcn_mfma_f32_16x16x32_bf16(A[m], Bv[j], acc[m][j], 0, 0, 0);
        }
        __builtin_amdgcn_s_setprio(0);

        #pragma unroll
        for (int m = 0; m < 2; ++m) {
            const int row0 = (wr*2 + m)*16 + lq*4;
            const int roff = (row0>>5)*1024 + ((row0&31)>>3)*256 + l15*16 + (row0&7)*2;
            float gmax[2][4];
            #pragma unroll
            for (int j = 0; j < 4; ++j) {
                const int g = j >> 1;
                u32x2 w;
                w[0] = pkbf(acc[m][j][0], acc[m][j][1]);
                w[1] = pkbf(acc[m][j][2], acc[m][j][3]);
                *(u32x2*)(sm + OFF_PF + (wc*4 + j)*8192 + roff) = w;
                #pragma unroll
                for (int r = 0; r < 4; ++r) {
                    if ((j & 1) == 0) gmax[g][r] = acc[m][j][r];
                    else              gmax[g][r] = fmaxf(gmax[g][r], acc[m][j][r]);
                }
            }
            #pragma unroll
            for (int s = 1; s < 16; s <<= 1)
                #pragma unroll
                for (int g = 0; g < 2; ++g)
                    #pragma unroll
                    for (int r = 0; r < 4; ++r)
                        gmax[g][r] = fmaxf(gmax[g][r], __shfl_xor(gmax[g][r], s));
            if (l15 < 2) {
                const int col = wc*2 + l15;            // global group 0..3
                u32x2 w;
                w[0] = pkbf(gmax[l15][0], gmax[l15][1]);
                w[1] = pkbf(gmax[l15][2], gmax[l15][3]);
                *(u32x2*)(sm + OFF_GF + (row0>>5)*256 + ((row0&31)>>3)*64 + col*16 + (row0&7)*2) = w;
            }
        }
    }
    __syncthreads();

    // ---- u = W3[:,0:256] @ gf  (N=16 MFMA; B cols = 4 groups, rest garbage) ----
    {
        f32x4 au[2];
        #pragma unroll
        for (int m = 0; m < 2; ++m) au[m] = (f32x4){0.f,0.f,0.f,0.f};

        const char* gfb = sm + OFF_GF + lq*64 + (l15 & 3)*16;
        __builtin_amdgcn_s_setprio(1);
        #pragma unroll 2
        for (int ks = 0; ks < 8; ++ks) {
            bf16x8 Bg = *(const bf16x8*)(gfb + ks*256);
            #pragma unroll
            for (int m = 0; m < 2; ++m) {
                bf16x8 A = *(const bf16x8*)(W3b + ((wave*2 + m)*16 + ks)*512 + lane*8);
                au[m] = __builtin_amdgcn_mfma_f32_16x16x32_bf16(A, Bg, au[m], 0, 0, 0);
            }
        }
        __builtin_amdgcn_s_setprio(0);
        if (l15 < 4) {
            float* u = (float*)(sm + OFF_U);
            #pragma unroll
            for (int m = 0; m < 2; ++m)
                #pragma unroll
                for (int r = 0; r < 4; ++r)
                    u[l15*512 + (wave*2 + m)*16 + lq*4 + r] = au[m][r];
        }
    }

    // ---- Layer 3 (MFMA, K=256 over pf): b3p folded; h2 = relu(acc + u) ----
    {
        f32x4 bias3[4];
        #pragma unroll
        for (int m = 0; m < 4; ++m)
            bias3[m] = *(const f32x4*)(b3p + (wr*4 + m)*16 + lq*4);

        f32x4 acc[4][4];
        #pragma unroll
        for (int m = 0; m < 4; ++m)
            #pragma unroll
            for (int j = 0; j < 4; ++j) acc[m][j] = bias3[m];

        __builtin_amdgcn_s_setprio(1);
        #pragma unroll 2
        for (int ks = 0; ks < 8; ++ks) {
            bf16x8 A[4], Bv[4];
            #pragma unroll
            for (int m = 0; m < 4; ++m)
                A[m] = *(const bf16x8*)(W3b + ((wr*4 + m)*16 + 8 + ks)*512 + lane*8);
            #pragma unroll
            for (int j = 0; j < 4; ++j)
                Bv[j] = *(const bf16x8*)(sm + OFF_PF + (wc*4 + j)*8192 + ks*1024 + lane*16);
            #pragma unroll
            for (int m = 0; m < 4; ++m)
                #pragma unroll
                for (int j = 0; j < 4; ++j)
                    acc[m][j] = __builtin_amdgcn_mfma_f32_16x16x32_bf16(A[m], Bv[j], acc[m][j], 0, 0, 0);
        }
        __builtin_amdgcn_s_setprio(0);

        __syncthreads();   // HT/PF reads done; U visible; H2 may overwrite alias region

        const float* u = (const float*)(sm + OFF_U);
        #pragma unroll
        for (int m = 0; m < 4; ++m) {
            const int row0 = (wr*4 + m)*16 + lq*4;
            const int roff = (row0>>5)*1024 + ((row0&31)>>3)*256 + l15*16 + (row0&7)*2;
            f32x4 u0 = *(const f32x4*)(u + (wc*2 + 0)*512 + row0);
            f32x4 u1 = *(const f32x4*)(u + (wc*2 + 1)*512 + row0);
            #pragma unroll
            for (int j = 0; j < 4; ++j) {
                const f32x4 ug = (j >> 1) ? u1 : u0;
                float v[4];
                #pragma unroll
                for (int r = 0; r < 4; ++r)
                    v[r] = fmaxf(acc[m][j][r] + ug[r], 0.f);
                u32x2 w;
                w[0] = pkbf(v[0], v[1]);
                w[1] = pkbf(v[2], v[3]);
                *(u32x2*)(sm + OFF_H2 + (wc*4 + j)*16384 + roff) = w;
            }
        }
    }
    __syncthreads();

    // ---- Layer 4 (MFMA, K=512): out = max_k (W4 h2) + b4 ----
    {
        f32x4 acc[3][4];
        #pragma unroll
        for (int m = 0; m < 3; ++m)
            #pragma unroll
            for (int j = 0; j < 4; ++j) acc[m][j] = (f32x4){0.f,0.f,0.f,0.f};

        __builtin_amdgcn_s_setprio(1);
        #pragma unroll 2
        for (int ks = 0; ks < 16; ++ks) {
            bf16x8 A[3], Bv[4];
            #pragma unroll
            for (int m = 0; m < 3; ++m)
                A[m] = *(const bf16x8*)(W4b + ((wr*3 + m)*16 + ks)*512 + lane*8);
            #pragma unroll
            for (int j = 0; j < 4; ++j)
                Bv[j] = *(const bf16x8*)(sm + OFF_H2 + (wc*4 + j)*16384 + ks*1024 + lane*16);
            #pragma unroll
            for (int m = 0; m < 3; ++m)
                #pragma unroll
                for (int j = 0; j < 4; ++j)
                    acc[m][j] = __builtin_amdgcn_mfma_f32_16x16x32_bf16(A[m], Bv[j], acc[m][j], 0, 0, 0);
        }
        __builtin_amdgcn_s_setprio(0);

        #pragma unroll
        for (int m = 0; m < 3; ++m) {
            const int row0 = (wr*3 + m)*16 + lq*4;
            float gmax[2][4];
            #pragma unroll
            for (int g = 0; g < 2; ++g)
                #pragma unroll
                for (int r = 0; r < 4; ++r)
                    gmax[g][r] = fmaxf(acc[m][2*g][r], acc[m][2*g+1][r]);
            #pragma unroll
            for (int s = 1; s < 16; s <<= 1)
                #pragma unroll
                for (int g = 0; g < 2; ++g)
                    #pragma unroll
                    for (int r = 0; r < 4; ++r)
                        gmax[g][r] = fmaxf(gmax[g][r], __shfl_xor(gmax[g][r], s));
            if (l15 < 2) {
                const int g = l15;                       // local; global group wc*2+g
                f32x4 b = *(const f32x4*)(b4 + row0);
                f32x4 o;
                #pragma unroll
                for (int r = 0; r < 4; ++r) o[r] = gmax[g][r] + b[r];
                *(f32x4*)(out + (size_t)(n0 + wc*2 + g) * 384 + row0) = o;
            }
        }
    }
}

extern "C" void kernel_launch(void* const* d_in, const int* in_sizes, int n_in,
                              void* d_out, int out_size, void* d_ws, size_t ws_size,
                              hipStream_t stream) {
    const float* pg  = (const float*)d_in[0];
    const float* W1  = (const float*)d_in[1];
    const float* b1  = (const float*)d_in[2];
    const float* g1  = (const float*)d_in[3];
    const float* be1 = (const float*)d_in[4];
    const float* m1  = (const float*)d_in[5];
    const float* v1  = (const float*)d_in[6];
    const float* W2  = (const float*)d_in[7];
    const float* b2  = (const float*)d_in[8];
    const float* W3  = (const float*)d_in[9];
    const float* b3  = (const float*)d_in[10];
    const float* g3  = (const float*)d_in[11];
    const float* be3 = (const float*)d_in[12];
    const float* m3  = (const float*)d_in[13];
    const float* v3  = (const float*)d_in[14];
    const float* W4  = (const float*)d_in[15];
    const float* b4  = (const float*)d_in[16];
    float* out = (float*)d_out;
    char* ws = (char*)d_ws;

    prep_kernel<<<dim3(256), dim3(256), 0, stream>>>(W1, b1, g1, be1, m1, v1, W2,
                                                     W3, b3, g3, be3, m3, v3, W4, ws);
    patch4_kernel<<<dim3(2048), dim3(1024), 0, stream>>>(pg, b2, b4, ws, out);
    (void)in_sizes; (void)n_in; (void)out_size; (void)ws_size;
}